// Round 8
// baseline (310.314 us; speedup 1.0000x reference)
//
#include <hip/hip_runtime.h>
#include <hip/hip_bf16.h>

// ThresholdEncode: x (N floats in [0,1)) -> (N, 64) float32 spike matrix.
// Row j (j < N-1): col 2i   = (x[j] <= th[i]) & (x[j+1] >  th[i])  (up)
//                  col 2i+1 = (x[j] >  th[i]) & (x[j+1] <= th[i])  (down)
// th[i] = float32((i+1) * (1/33) in double)  -- matches np.linspace. Last row 0.
//
// === DIAGNOSTIC ROUND 2 ===
// R7 learned: same-address double-store is L2-absorbed (free) => kernel ~87us
// is pure HBM drain at ~3.0 TB/s vs fill's 6.6 TB/s. To finally capture OUR
// dispatch's counters, pass 2 now stores to d_ws (different addresses, real
// HBM traffic) -> our dispatch becomes the slowest (~175+us), enters top-5.
//   FETCH_SIZE ~500MB => store RFO confirmed (the 2x theory)
//   FETCH_SIZE small  => no RFO; read Occupancy/VALUBusy instead
// NOTE: nontemporal stores LOST WRITES under graph replay (round 3) — plain
// stores only.

typedef float f32x4 __attribute__((ext_vector_type(4)));

__global__ __launch_bounds__(256) void ThresholdEncode_kernel(
    const float* __restrict__ x, f32x4* __restrict__ out,
    f32x4* __restrict__ ws, int n, int do_ws) {
    const int t = blockIdx.x * 256 + threadIdx.x;
    const int ngroups = (n + 7) >> 3;          // groups of 8 rows
    if (t >= ngroups * 16) return;
    const int c  = t & 15;                     // quad (4 cols) within row
    const int g  = t >> 4;                     // row group
    const int j0 = g << 3;                     // first row of group

    // Exact np.linspace(0,1,34,f32)[1:-1]: compute in double, round once.
    const float t0 = (float)((double)(2 * c + 1) * (1.0 / 33.0));
    const float t1 = (float)((double)(2 * c + 2) * (1.0 / 33.0));

    // Load x[j0 .. j0+8] : two aligned float4 + one boundary scalar.
    float xv[9];
    if (j0 + 8 <= n) {
        const f32x4 a = *(const f32x4*)(x + j0);
        const f32x4 b = *(const f32x4*)(x + j0 + 4);
        xv[0]=a.x; xv[1]=a.y; xv[2]=a.z; xv[3]=a.w;
        xv[4]=b.x; xv[5]=b.y; xv[6]=b.z; xv[7]=b.w;
        xv[8] = (j0 + 8 < n) ? x[j0 + 8] : 0.0f;
    } else {
        #pragma unroll
        for (int k = 0; k < 9; ++k) xv[k] = (j0 + k < n) ? x[j0 + k] : 0.0f;
    }

    // Compute all 8 output quads into registers (static indexing).
    f32x4 vv[8];
    #pragma unroll
    for (int k = 0; k < 8; ++k) {
        f32x4 v = (f32x4)(0.f, 0.f, 0.f, 0.f);
        if (j0 + k < n - 1) {
            const float xp = xv[k];
            const float xn = xv[k + 1];
            v.x = (xp <= t0 && xn >  t0) ? 1.0f : 0.0f;
            v.y = (xp >  t0 && xn <= t0) ? 1.0f : 0.0f;
            v.z = (xp <= t1 && xn >  t1) ? 1.0f : 0.0f;
            v.w = (xp >  t1 && xn <= t1) ? 1.0f : 0.0f;
        }
        vv[k] = v;
    }

    // Pass 1: real output.
    #pragma unroll
    for (int k = 0; k < 8; ++k)
        if (j0 + k < n) out[(j0 + k) * 16 + c] = vv[k];

    asm volatile("" ::: "memory");

    // Pass 2: same data to scratch (different HBM addresses) — forces our
    // dispatch's real write BW to show up in the profile. Same work each call.
    if (do_ws) {
        #pragma unroll
        for (int k = 0; k < 8; ++k)
            if (j0 + k < n) ws[(j0 + k) * 16 + c] = vv[k];
    }
}

extern "C" void kernel_launch(void* const* d_in, const int* in_sizes, int n_in,
                              void* d_out, int out_size, void* d_ws, size_t ws_size,
                              hipStream_t stream) {
    const float* x = (const float*)d_in[0];
    f32x4* out = (f32x4*)d_out;
    f32x4* ws  = (f32x4*)d_ws;
    const int n = in_sizes[0];                 // 1,000,000
    const int do_ws = (ws_size >= (size_t)n * 16 * sizeof(f32x4)) ? 1 : 0;
    const int ngroups = (n + 7) >> 3;          // 125,000
    const int threads = ngroups * 16;          // 2,000,000
    const int block = 256;
    const int grid = (threads + block - 1) / block;  // 7,813 blocks
    ThresholdEncode_kernel<<<grid, block, 0, stream>>>(x, out, ws, n, do_ws);
}